// Round 3
// baseline (21347.073 us; speedup 1.0000x reference)
//
#include <hip/hip_runtime.h>
#include <math.h>

#define N_NODES 10000
#define N_EDGES 320000

// persistent-grid geometry: 1024 blocks x 256 threads = 4096 waves.
// __launch_bounds__(256,6) -> VGPR<=84 (achieved 64 in r2) -> >=6 waves/SIMD;
// residency needs only 4 blocks/CU avg (1024/256): guaranteed with margin.
#define NBLK 1024
#define NTHR 256
#define WAVES_PER_XCD 512   // (NBLK/8 blocks/XCD) * (NTHR/64 waves/block)
#define NODES_PER_XCD 1250  // N_NODES / 8

// ---------------- barrier state ----------------
// 16-way striped arrival tree: 16 leaves (64 contenders each) -> root (16) -> 16 go words.
// Blocks b = s mod 16 share a leaf AND an XCD (b&7) -> leaf RMWs stay XCD-local-ish.
struct alignas(256) PadInt { int v; int _p[63]; };
struct Bar { PadInt leaf[16]; PadInt root; PadInt go[16]; };  // 33 * 256 B
#define BAR_INTS (33 * 64)                   // ints per Bar = 2112
#define BAR_REGION_INTS (3 * BAR_INTS + 64)  // 3 layer barriers + padded abort word

// ---------------- setup kernels ----------------

__global__ void k_init(float* deg, int* cnt, int* fill, int* barmem, int n) {
    int i = blockIdx.x * blockDim.x + threadIdx.x;
    if (i < n) { deg[i] = 0.f; cnt[i] = 0; fill[i] = 0; }
    if (i < BAR_REGION_INTS) barmem[i] = 0;
}

__global__ void k_deg(const int* __restrict__ ei, const float* __restrict__ w,
                      float* deg, int E) {
    int e = blockIdx.x * blockDim.x + threadIdx.x;
    if (e < E) atomicAdd(&deg[ei[e]], w[e]);
}

__global__ void k_dis(float* deg, int n) {
    int i = blockIdx.x * blockDim.x + threadIdx.x;
    if (i < n) {
        float d = deg[i];
        deg[i] = (d > 0.f) ? (float)(1.0 / sqrt((double)d)) : 0.f;
    }
}

__global__ void k_norm(const int* __restrict__ ei, const float* __restrict__ w,
                       const float* __restrict__ dis, float* __restrict__ normw,
                       int* cnt, int E) {
    int e = blockIdx.x * blockDim.x + threadIdx.x;
    if (e < E) {
        int s = ei[e], d = ei[E + e];
        normw[e] = -dis[s] * w[e] * dis[d];
        atomicAdd(&cnt[d], 1);
    }
}

// single-block exclusive scan over counts -> rowptr[0..n]
__global__ void k_scan(const int* __restrict__ cnt, int* __restrict__ rowptr, int n) {
    __shared__ int part[1024];
    const int PER = 10;  // 1024*10 >= n
    int t = threadIdx.x;
    int base = t * PER;
    int local[PER];
    int s = 0;
    for (int j = 0; j < PER; j++) {
        int idx = base + j;
        int v = (idx < n) ? cnt[idx] : 0;
        local[j] = v; s += v;
    }
    part[t] = s;
    __syncthreads();
    for (int off = 1; off < 1024; off <<= 1) {
        int v = part[t];
        int u = (t >= off) ? part[t - off] : 0;
        __syncthreads();
        part[t] = v + u;
        __syncthreads();
    }
    int excl = (t > 0) ? part[t - 1] : 0;
    for (int j = 0; j < PER; j++) {
        int idx = base + j;
        if (idx < n) rowptr[idx] = excl;
        excl += local[j];
    }
    if (t == 1023) rowptr[n] = part[1023];
}

// pair CSR: {src byte-offset (stride-64 rows), norm bits}
__global__ void k_fill(const int* __restrict__ ei, const float* __restrict__ normw,
                       const int* __restrict__ rowptr, int* fill,
                       int2* __restrict__ pr, int E) {
    int e = blockIdx.x * blockDim.x + threadIdx.x;
    if (e < E) {
        int d = ei[E + e];
        int pos = atomicAdd(&fill[d], 1);
        int idx = rowptr[d] + pos;
        pr[idx] = make_int2(ei[e] << 8, __float_as_int(normw[e]));
    }
}

// ---------------- grid barrier v3 ----------------
// 16-way striped monotonic tree; per-block release before arrival, acquire after
// exit (proven cheap on gfx950 per r1 narrow counters); short-backoff polling.
__device__ __forceinline__ bool gridbar(Bar* __restrict__ B, int* __restrict__ abortf,
                                        int phase) {
    __shared__ int ok_s;
    __syncthreads();
    if (threadIdx.x == 0) {
        int s = blockIdx.x & 15;
        __builtin_amdgcn_fence(__ATOMIC_RELEASE, "agent");  // drain stores
        int old = __hip_atomic_fetch_add(&B->leaf[s].v, 1,
                                         __ATOMIC_RELAXED, __HIP_MEMORY_SCOPE_AGENT);
        if (old + 1 == phase * (NBLK / 16)) {  // last arriver of this stripe
            int r = __hip_atomic_fetch_add(&B->root.v, 1,
                                           __ATOMIC_RELAXED, __HIP_MEMORY_SCOPE_AGENT);
            if (r + 1 == phase * 16) {  // last stripe: publish
#pragma unroll
                for (int j = 0; j < 16; j++)
                    __hip_atomic_store(&B->go[j].v, phase,
                                       __ATOMIC_RELAXED, __HIP_MEMORY_SCOPE_AGENT);
            }
        }
        int ok = 1, spins = 0;
        while (__hip_atomic_load(&B->go[s].v, __ATOMIC_RELAXED,
                                 __HIP_MEMORY_SCOPE_AGENT) < phase) {
            if (spins < 16) __builtin_amdgcn_s_sleep(2);    // ~0.05 us
            else            __builtin_amdgcn_s_sleep(16);   // ~0.4 us
            if ((++spins & 63) == 0) {
                if (__hip_atomic_load(abortf, __ATOMIC_RELAXED,
                                      __HIP_MEMORY_SCOPE_AGENT)) { ok = 0; break; }
                if (spins > (1 << 18)) {  // ~0.1 s: residency failure -> abort all
                    __hip_atomic_store(abortf, 1, __ATOMIC_RELAXED,
                                       __HIP_MEMORY_SCOPE_AGENT);
                    ok = 0; break;
                }
            }
        }
        __builtin_amdgcn_fence(__ATOMIC_ACQUIRE, "agent");
        ok_s = ok;
    }
    __syncthreads();
    return ok_s != 0;
}

// ---------------- gathers ----------------
// wide: lane = channel (stride-64 float rows). Batch-8 pipelined loads.
__device__ __forceinline__ float gather_w(const char* __restrict__ tb,
                                          const int2* __restrict__ pr,
                                          int rb, int dg, int lane4) {
    float agg = 0.f;
    int e = 0;
    for (; e + 8 <= dg; e += 8) {
        int2 p[8]; float v[8];
#pragma unroll
        for (int u = 0; u < 8; u++) p[u] = pr[rb + e + u];
#pragma unroll
        for (int u = 0; u < 8; u++)
            v[u] = *(const float*)(tb + (unsigned)p[u].x + lane4);
#pragma unroll
        for (int u = 0; u < 8; u++)
            agg = fmaf(__int_as_float(p[u].y), v[u], agg);
    }
    if (e < dg) {  // masked batch-8 tail: stays pipelined
        int2 p[8]; float v[8];
#pragma unroll
        for (int u = 0; u < 8; u++) p[u] = pr[(e + u < dg) ? (rb + e + u) : rb];
#pragma unroll
        for (int u = 0; u < 8; u++)
            v[u] = *(const float*)(tb + (unsigned)p[u].x + lane4);
#pragma unroll
        for (int u = 0; u < 8; u++) {
            float w = (e + u < dg) ? __int_as_float(p[u].y) : 0.f;
            agg = fmaf(w, v[u], agg);
        }
    }
    return agg;
}

// narrow (stride-4 float rows): lane = eo*4+lc, 16 edges in parallel, batch-2.
// pair offset is src<<8; stride-4 byte offset = src<<4 = off>>4.
__device__ __forceinline__ float gather_n(const char* __restrict__ tb,
                                          const int2* __restrict__ pr,
                                          int rb, int dg, int lc4, int eo) {
    float agg = 0.f;
    int e = eo;
    for (; e + 32 <= dg; e += 32) {
        int2 p0 = pr[rb + e];
        int2 p1 = pr[rb + e + 16];
        float v0 = *(const float*)(tb + ((unsigned)p0.x >> 4) + lc4);
        float v1 = *(const float*)(tb + ((unsigned)p1.x >> 4) + lc4);
        agg = fmaf(__int_as_float(p0.y), v0, agg);
        agg = fmaf(__int_as_float(p1.y), v1, agg);
    }
    for (; e < dg; e += 16) {
        int2 p = pr[rb + e];
        agg = fmaf(__int_as_float(p.y),
                   *(const float*)(tb + ((unsigned)p.x >> 4) + lc4), agg);
    }
    agg += __shfl_xor(agg, 4);
    agg += __shfl_xor(agg, 8);
    agg += __shfl_xor(agg, 16);
    agg += __shfl_xor(agg, 32);
    return agg;  // channel lc, replicated across eo groups
}

// ---------------- dense: acc(lane=o) += sum_c t2(c) * W[c][o] ----------------
template <int CI, int CO>
__device__ __forceinline__ void dense(float& acc, float t2v,
                                      const float* __restrict__ Wk, int lane) {
#pragma unroll
    for (int c = 0; c < CI; c++) {
        float tb = __int_as_float(__builtin_amdgcn_readlane(__float_as_int(t2v), c));
        float wv;
        if (CO < 64) wv = (lane < CO) ? Wk[c * CO + lane] : 0.f;
        else         wv = Wk[c * CO + lane];
        acc = fmaf(tb, wv, acc);
    }
}

// ---------------- persistent layer kernels ----------------
// Each wave owns 2-3 nodes for the whole K-recurrence; acc / T_{k-2} / T_{k-1}
// (own-node) stay in registers; only T_{k-1} rows are published (non-temporal
// stores: avoid shared-dirty L2 lines -> no coherence-probe storms) to a 2-deep
// rotating global buffer with one grid barrier per step.

// wide: CI in {64,60}, rows stride 64. LAST 1: silu->outp(n x 64); 2: silu+W4+sigmoid->outp(n).
template <int CI, int CO, int KK, int LAST>
__global__ __launch_bounds__(NTHR, 6) void layer_wide(
    const int* __restrict__ rowptr, const int2* __restrict__ pr,
    const float* __restrict__ hin,
    float* __restrict__ tA, float* __restrict__ tB,
    const float* __restrict__ W, const float* __restrict__ bias,
    const float* __restrict__ W4, float* __restrict__ outp,
    Bar* __restrict__ bar, int* __restrict__ abortf)
{
    int tid = threadIdx.x;
    int lane = tid & 63;
    int lane4 = lane * 4;
    int b = blockIdx.x;
    int xcd = b & 7;
    int wix = (b >> 3) * (NTHR / 64) + (tid >> 6);  // 0..511 within XCD

    int n0 = xcd * NODES_PER_XCD + wix;
    int n1 = n0 + WAVES_PER_XCD;
    bool has2 = wix < (NODES_PER_XCD - 2 * WAVES_PER_XCD);  // wix < 226
    int n2 = n0 + 2 * WAVES_PER_XCD;

    int rb0 = rowptr[n0], dg0 = rowptr[n0 + 1] - rb0;
    int rb1 = rowptr[n1], dg1 = rowptr[n1 + 1] - rb1;
    int rb2 = 0, dg2 = 0;
    if (has2) { rb2 = rowptr[n2]; dg2 = rowptr[n2 + 1] - rb2; }

    float acc0, acc1, acc2 = 0.f;
    float p0, p1, p2 = 0.f;   // T_{k-2} own value
    float q0, q1, q2 = 0.f;   // T_{k-1} own value

#define K01W(nid, rb, dg, acc, t0v, t1v) {                         \
        float hr = hin[(nid) * 64 + lane];                         \
        float a = (lane < CO) ? bias[lane] : 0.f;                  \
        dense<CI, CO>(a, hr, W, lane);                             \
        float g = gather_w((const char*)hin, pr, rb, dg, lane4);   \
        dense<CI, CO>(a, g, W + CI * CO, lane);                    \
        __builtin_nontemporal_store(g, &tB[(nid) * 64 + lane]);    \
        acc = a; t0v = hr; t1v = g; }

#define STEPW(nid, rb, dg, acc, t0v, t1v) {                        \
        float g = gather_w((const char*)rd, pr, rb, dg, lane4);    \
        float t2 = fmaf(2.f, g, -t0v);                             \
        dense<CI, CO>(acc, t2, Wk, lane);                          \
        if (!lastk) {                                              \
            __builtin_nontemporal_store(t2, &wr[(nid) * 64 + lane]); \
            t0v = t1v; t1v = t2; } }

    int phase = 0;
    K01W(n0, rb0, dg0, acc0, p0, q0);
    K01W(n1, rb1, dg1, acc1, p1, q1);
    if (has2) K01W(n2, rb2, dg2, acc2, p2, q2);
    if (!gridbar(bar, abortf, ++phase)) return;

    for (int k = 2; k < KK; k++) {
        const float* rd = (k & 1) ? tA : tB;   // buf[(k-1)%2]
        float* wr = (k & 1) ? tB : tA;         // buf[k%2] (read at k-1; sync separates)
        const float* Wk = W + (size_t)k * (CI * CO);
        const bool lastk = (k == KK - 1);
        STEPW(n0, rb0, dg0, acc0, p0, q0);
        STEPW(n1, rb1, dg1, acc1, p1, q1);
        if (has2) STEPW(n2, rb2, dg2, acc2, p2, q2);
        if (!lastk) { if (!gridbar(bar, abortf, ++phase)) return; }
    }

#define EPIW(nid, acc) {                                           \
        float a = acc;                                             \
        if (LAST == 1) {                                           \
            outp[(nid) * 64 + lane] = a / (1.f + expf(-a));        \
        } else {                                                   \
            float h = a / (1.f + expf(-a));                        \
            float w4 = (lane < 30) ? W4[lane] : 0.f;               \
            float pp = h * w4;                                     \
            pp += __shfl_xor(pp, 1);                               \
            pp += __shfl_xor(pp, 2);                               \
            pp += __shfl_xor(pp, 4);                               \
            pp += __shfl_xor(pp, 8);                               \
            pp += __shfl_xor(pp, 16);                              \
            pp += __shfl_xor(pp, 32);                              \
            if (lane == 0) outp[nid] = 1.f / (1.f + expf(-pp));    \
        } }

    EPIW(n0, acc0);
    EPIW(n1, acc1);
    if (has2) EPIW(n2, acc2);
#undef K01W
#undef STEPW
#undef EPIW
}

// narrow: layer 1 (4 -> 64), rows stride 4. Output: silu -> outp (n x 64).
template <int KK>
__global__ __launch_bounds__(NTHR, 6) void layer_narrow(
    const int* __restrict__ rowptr, const int2* __restrict__ pr,
    const float* __restrict__ xin,
    float* __restrict__ tA, float* __restrict__ tB,
    const float* __restrict__ W, const float* __restrict__ bias,
    float* __restrict__ outp,
    Bar* __restrict__ bar, int* __restrict__ abortf)
{
    int tid = threadIdx.x;
    int lane = tid & 63;
    int lc = lane & 3, eo = lane >> 2, lc4 = lc * 4;
    int b = blockIdx.x;
    int xcd = b & 7;
    int wix = (b >> 3) * (NTHR / 64) + (tid >> 6);

    int n0 = xcd * NODES_PER_XCD + wix;
    int n1 = n0 + WAVES_PER_XCD;
    bool has2 = wix < (NODES_PER_XCD - 2 * WAVES_PER_XCD);
    int n2 = n0 + 2 * WAVES_PER_XCD;

    int rb0 = rowptr[n0], dg0 = rowptr[n0 + 1] - rb0;
    int rb1 = rowptr[n1], dg1 = rowptr[n1 + 1] - rb1;
    int rb2 = 0, dg2 = 0;
    if (has2) { rb2 = rowptr[n2]; dg2 = rowptr[n2 + 1] - rb2; }

    float acc0, acc1, acc2 = 0.f;
    float p0, p1, p2 = 0.f;
    float q0, q1, q2 = 0.f;

#define K01N(nid, rb, dg, acc, t0v, t1v) {                           \
        float xr = xin[(nid) * 4 + lc];                              \
        float a = bias[lane];                                        \
        dense<4, 64>(a, xr, W, lane);                                \
        float g = gather_n((const char*)xin, pr, rb, dg, lc4, eo);   \
        dense<4, 64>(a, g, W + 4 * 64, lane);                        \
        if (lane < 4) __builtin_nontemporal_store(g, &tB[(nid) * 4 + lane]); \
        acc = a; t0v = xr; t1v = g; }

#define STEPN(nid, rb, dg, acc, t0v, t1v) {                          \
        float g = gather_n((const char*)rd, pr, rb, dg, lc4, eo);    \
        float t2 = fmaf(2.f, g, -t0v);                               \
        dense<4, 64>(acc, t2, Wk, lane);                             \
        if (!lastk) {                                                \
            if (lane < 4) __builtin_nontemporal_store(t2, &wr[(nid) * 4 + lane]); \
            t0v = t1v; t1v = t2; } }

    int phase = 0;
    K01N(n0, rb0, dg0, acc0, p0, q0);
    K01N(n1, rb1, dg1, acc1, p1, q1);
    if (has2) K01N(n2, rb2, dg2, acc2, p2, q2);
    if (!gridbar(bar, abortf, ++phase)) return;

    for (int k = 2; k < KK; k++) {
        const float* rd = (k & 1) ? tA : tB;
        float* wr = (k & 1) ? tB : tA;
        const float* Wk = W + (size_t)k * (4 * 64);
        const bool lastk = (k == KK - 1);
        STEPN(n0, rb0, dg0, acc0, p0, q0);
        STEPN(n1, rb1, dg1, acc1, p1, q1);
        if (has2) STEPN(n2, rb2, dg2, acc2, p2, q2);
        if (!lastk) { if (!gridbar(bar, abortf, ++phase)) return; }
    }

    outp[n0 * 64 + lane] = acc0 / (1.f + expf(-acc0));
    outp[n1 * 64 + lane] = acc1 / (1.f + expf(-acc1));
    if (has2) outp[n2 * 64 + lane] = acc2 / (1.f + expf(-acc2));
#undef K01N
#undef STEPN
}

// ---------------- host ----------------

extern "C" void kernel_launch(void* const* d_in, const int* in_sizes, int n_in,
                              void* d_out, int out_size, void* d_ws, size_t ws_size,
                              hipStream_t stream) {
    const float* x  = (const float*)d_in[0];
    const int*   ei = (const int*)d_in[1];
    const float* ew = (const float*)d_in[2];
    const float* W1 = (const float*)d_in[3];
    const float* b1 = (const float*)d_in[4];
    const float* W2 = (const float*)d_in[5];
    const float* b2 = (const float*)d_in[6];
    const float* W3 = (const float*)d_in[7];
    const float* b3 = (const float*)d_in[8];
    const float* W4 = (const float*)d_in[9];
    float* out = (float*)d_out;

    const int n = N_NODES, E = N_EDGES;

    char* ws = (char*)d_ws;
    size_t off = 0;
    auto alloc = [&](size_t bytes) -> void* {
        void* p = ws + off;
        off += (bytes + 255) & ~(size_t)255;
        return p;
    };
    float* deg    = (float*)alloc(n * 4);     // becomes dis in-place
    int*   cnt    = (int*)alloc(n * 4);
    int*   fill   = (int*)alloc(n * 4);
    int*   rowptr = (int*)alloc((n + 4) * 4);
    float* normw  = (float*)alloc((size_t)E * 4);
    int2*  pr     = (int2*)alloc((size_t)E * 8);
    int*   barmem = (int*)alloc(BAR_REGION_INTS * 4);
    float* t4a  = (float*)alloc(n * 4 * 4);
    float* t4b  = (float*)alloc(n * 4 * 4);
    float* tba  = (float*)alloc(n * 64 * 4);
    float* tbb  = (float*)alloc(n * 64 * 4);
    float* h1   = (float*)alloc(n * 64 * 4);
    float* h2   = (float*)alloc(n * 64 * 4);
    (void)ws_size; (void)n_in; (void)in_sizes; (void)out_size;

    Bar* bar1 = (Bar*)barmem;
    Bar* bar2 = bar1 + 1;
    Bar* bar3 = bar1 + 2;
    int* abortf = barmem + 3 * BAR_INTS;  // padded line after the 3 Bars

    // ---- preprocessing: degree, norm, dst-sorted pair-CSR ----
    k_init<<<(n + 255) / 256, 256, 0, stream>>>(deg, cnt, fill, barmem, n);
    k_deg <<<(E + 255) / 256, 256, 0, stream>>>(ei, ew, deg, E);
    k_dis <<<(n + 255) / 256, 256, 0, stream>>>(deg, n);
    k_norm<<<(E + 255) / 256, 256, 0, stream>>>(ei, ew, deg, normw, cnt, E);
    k_scan<<<1, 1024, 0, stream>>>(cnt, rowptr, n);
    k_fill<<<(E + 255) / 256, 256, 0, stream>>>(ei, normw, rowptr, fill, pr, E);

    // ---- Layer 1: K=120, 4 -> 64, silu -> h1 (persistent) ----
    layer_narrow<120><<<NBLK, NTHR, 0, stream>>>(
        rowptr, pr, x, t4a, t4b, W1, b1, h1, bar1, abortf);

    // ---- Layer 2: K=120, 64 -> 60, silu -> h2 (persistent) ----
    layer_wide<64, 60, 120, 1><<<NBLK, NTHR, 0, stream>>>(
        rowptr, pr, h1, tba, tbb, W2, b2, nullptr, h2, bar2, abortf);

    // ---- Layer 3 (K=20, 60 -> 30, silu) + fused Layer 4 (30 -> 1, sigmoid) ----
    layer_wide<60, 30, 20, 2><<<NBLK, NTHR, 0, stream>>>(
        rowptr, pr, h2, tba, tbb, W3, b3, W4, out, bar3, abortf);
}

// Round 4
// 3431.680 us; speedup vs baseline: 6.2206x; 6.2206x over previous
//
#include <hip/hip_runtime.h>
#include <math.h>

#define N_NODES 10000
#define N_EDGES 320000

// ---------------- setup kernels ----------------

__global__ void k_init(float* deg, int* cnt, int* fill, int n) {
    int i = blockIdx.x * blockDim.x + threadIdx.x;
    if (i < n) { deg[i] = 0.f; cnt[i] = 0; fill[i] = 0; }
}

__global__ void k_deg(const int* __restrict__ ei, const float* __restrict__ w,
                      float* deg, int E) {
    int e = blockIdx.x * blockDim.x + threadIdx.x;
    if (e < E) atomicAdd(&deg[ei[e]], w[e]);
}

__global__ void k_dis(float* deg, int n) {
    int i = blockIdx.x * blockDim.x + threadIdx.x;
    if (i < n) {
        float d = deg[i];
        deg[i] = (d > 0.f) ? (float)(1.0 / sqrt((double)d)) : 0.f;
    }
}

__global__ void k_norm(const int* __restrict__ ei, const float* __restrict__ w,
                       const float* __restrict__ dis, float* __restrict__ normw,
                       int* cnt, int E) {
    int e = blockIdx.x * blockDim.x + threadIdx.x;
    if (e < E) {
        int s = ei[e], d = ei[E + e];
        normw[e] = -dis[s] * w[e] * dis[d];
        atomicAdd(&cnt[d], 1);
    }
}

// single-block exclusive scan over counts -> rowptr[0..n]
__global__ void k_scan(const int* __restrict__ cnt, int* __restrict__ rowptr, int n) {
    __shared__ int part[1024];
    const int PER = 10;  // 1024*10 >= n
    int t = threadIdx.x;
    int base = t * PER;
    int local[PER];
    int s = 0;
    for (int j = 0; j < PER; j++) {
        int idx = base + j;
        int v = (idx < n) ? cnt[idx] : 0;
        local[j] = v; s += v;
    }
    part[t] = s;
    __syncthreads();
    for (int off = 1; off < 1024; off <<= 1) {
        int v = part[t];
        int u = (t >= off) ? part[t - off] : 0;
        __syncthreads();
        part[t] = v + u;
        __syncthreads();
    }
    int excl = (t > 0) ? part[t - 1] : 0;
    for (int j = 0; j < PER; j++) {
        int idx = base + j;
        if (idx < n) rowptr[idx] = excl;
        excl += local[j];
    }
    if (t == 1023) rowptr[n] = part[1023];
}

// pair CSR: {src byte-offset (stride-64 rows), norm bits}
__global__ void k_fill(const int* __restrict__ ei, const float* __restrict__ normw,
                       const int* __restrict__ rowptr, int* fill,
                       int2* __restrict__ pr, int E) {
    int e = blockIdx.x * blockDim.x + threadIdx.x;
    if (e < E) {
        int d = ei[E + e];
        int pos = atomicAdd(&fill[d], 1);
        int idx = rowptr[d] + pos;
        pr[idx] = make_int2(ei[e] << 8, __float_as_int(normw[e]));
    }
}

// ---------------- gathers ----------------
// wide single-stream continuation: batch-8 pipelined from offset e (same FP
// order as the r0 kernel: ascending batches of 8, masked batch-8 tail).
__device__ __forceinline__ float gather_w_from(const char* __restrict__ tb,
                                               const int2* __restrict__ pr,
                                               int rb, int e, int dg, int lane4,
                                               float agg) {
    for (; e + 8 <= dg; e += 8) {
        int2 p[8]; float v[8];
#pragma unroll
        for (int u = 0; u < 8; u++) p[u] = pr[rb + e + u];
#pragma unroll
        for (int u = 0; u < 8; u++)
            v[u] = *(const float*)(tb + (unsigned)p[u].x + lane4);
#pragma unroll
        for (int u = 0; u < 8; u++)
            agg = fmaf(__int_as_float(p[u].y), v[u], agg);
    }
    if (e < dg) {  // masked batch-8 tail: stays pipelined
        int2 p[8]; float v[8];
#pragma unroll
        for (int u = 0; u < 8; u++) p[u] = pr[(e + u < dg) ? (rb + e + u) : rb];
#pragma unroll
        for (int u = 0; u < 8; u++)
            v[u] = *(const float*)(tb + (unsigned)p[u].x + lane4);
#pragma unroll
        for (int u = 0; u < 8; u++) {
            float w = (e + u < dg) ? __int_as_float(p[u].y) : 0.f;
            agg = fmaf(w, v[u], agg);
        }
    }
    return agg;
}

// dual-stream wide gather: two nodes' edge lists interleaved batch-8/batch-8
// (16 loads in flight), identical per-node FP order to the single-stream path.
__device__ __forceinline__ void gather_w2(const char* __restrict__ tb,
                                          const int2* __restrict__ pr,
                                          int rb0, int dg0, int rb1, int dg1,
                                          int lane4, float& o0, float& o1) {
    float a0 = 0.f, a1 = 0.f;
    int e0 = 0, e1 = 0;
    while (e0 + 8 <= dg0 && e1 + 8 <= dg1) {
        int2 p0[8], p1[8]; float v0[8], v1[8];
#pragma unroll
        for (int u = 0; u < 8; u++) { p0[u] = pr[rb0 + e0 + u]; p1[u] = pr[rb1 + e1 + u]; }
#pragma unroll
        for (int u = 0; u < 8; u++) {
            v0[u] = *(const float*)(tb + (unsigned)p0[u].x + lane4);
            v1[u] = *(const float*)(tb + (unsigned)p1[u].x + lane4);
        }
#pragma unroll
        for (int u = 0; u < 8; u++) {
            a0 = fmaf(__int_as_float(p0[u].y), v0[u], a0);
            a1 = fmaf(__int_as_float(p1[u].y), v1[u], a1);
        }
        e0 += 8; e1 += 8;
    }
    o0 = gather_w_from(tb, pr, rb0, e0, dg0, lane4, a0);
    o1 = gather_w_from(tb, pr, rb1, e1, dg1, lane4, a1);
}

// narrow (stride-4 float rows): lane = eo*4+lc, 16 edges in parallel, batch-2.
// pair offset is src<<8; stride-4 byte offset = src<<4 = off>>4.
__device__ __forceinline__ float gather_n(const char* __restrict__ tb,
                                          const int2* __restrict__ pr,
                                          int rb, int dg, int lc4, int eo) {
    float agg = 0.f;
    int e = eo;
    for (; e + 32 <= dg; e += 32) {
        int2 p0 = pr[rb + e];
        int2 p1 = pr[rb + e + 16];
        float v0 = *(const float*)(tb + ((unsigned)p0.x >> 4) + lc4);
        float v1 = *(const float*)(tb + ((unsigned)p1.x >> 4) + lc4);
        agg = fmaf(__int_as_float(p0.y), v0, agg);
        agg = fmaf(__int_as_float(p1.y), v1, agg);
    }
    for (; e < dg; e += 16) {
        int2 p = pr[rb + e];
        agg = fmaf(__int_as_float(p.y),
                   *(const float*)(tb + ((unsigned)p.x >> 4) + lc4), agg);
    }
    agg += __shfl_xor(agg, 4);
    agg += __shfl_xor(agg, 8);
    agg += __shfl_xor(agg, 16);
    agg += __shfl_xor(agg, 32);
    return agg;  // channel lc, replicated across eo groups
}

// ---------------- dense (dual-node, W from LDS) ----------------
// acc(lane=o) += sum_c t2(c) * W[c][o]; one sW read feeds both nodes.
template <int CI, int CO>
__device__ __forceinline__ void dense2(float& a0, float x0, float& a1, float x1,
                                       const float* sW, int lane) {
#pragma unroll
    for (int c = 0; c < CI; c++) {
        float w;
        if (CO < 64) w = (lane < CO) ? sW[c * CO + lane] : 0.f;
        else         w = sW[c * CO + lane];
        float b0 = __int_as_float(__builtin_amdgcn_readlane(__float_as_int(x0), c));
        float b1 = __int_as_float(__builtin_amdgcn_readlane(__float_as_int(x1), c));
        a0 = fmaf(b0, w, a0);
        a1 = fmaf(b1, w, a1);
    }
}

// ---------------- step kernels: one wave per TWO nodes ----------------
// MODE 1: fused k0+k1  (acc = b + h@W0 + prop(h)@W1, publish T1)
// MODE 2: recurrence   (T2 = 2*prop(T1) - T0, acc += T2@Wk, publish T2)
// LAST 0: store acc + publish; 1: silu -> hout (n x 64); 2: silu + layer4 sigmoid -> out

template <int CI, int CO, int MODE, int LAST>
__global__ __launch_bounds__(256, 6) void k_wide(
    const int* __restrict__ rowptr, const int2* __restrict__ pr,
    const float* __restrict__ hin,
    const float* __restrict__ t0, const float* __restrict__ t1,
    float* __restrict__ t2, float* __restrict__ accb,
    const float* __restrict__ Wk, const float* __restrict__ bias,
    const float* __restrict__ W4, float* __restrict__ outp)
{
    __shared__ float sW[(MODE == 1 ? 2 : 1) * CI * CO];
    int tid = threadIdx.x;
    const int NW = (MODE == 1 ? 2 : 1) * CI * CO;
    for (int i = tid; i < NW; i += 256) sW[i] = Wk[i];
    __syncthreads();

    int lane = tid & 63;
    int lane4 = lane * 4;
    int node0 = blockIdx.x * 8 + (tid >> 6) * 2;
    int node1 = node0 + 1;
    int rb0 = rowptr[node0], dg0 = rowptr[node0 + 1] - rb0;
    int rb1 = rowptr[node1], dg1 = rowptr[node1 + 1] - rb1;

    float acc0, acc1, t2v0, t2v1;
    if (MODE == 1) {
        float h0 = hin[node0 * 64 + lane];
        float h1 = hin[node1 * 64 + lane];
        float b = (lane < CO) ? bias[lane] : 0.f;
        acc0 = b; acc1 = b;
        dense2<CI, CO>(acc0, h0, acc1, h1, sW, lane);
        gather_w2((const char*)hin, pr, rb0, dg0, rb1, dg1, lane4, t2v0, t2v1);
        dense2<CI, CO>(acc0, t2v0, acc1, t2v1, sW + CI * CO, lane);
    } else {
        acc0 = accb[node0 * 64 + lane];
        acc1 = accb[node1 * 64 + lane];
        float t00 = t0[node0 * 64 + lane];
        float t01 = t0[node1 * 64 + lane];
        float g0, g1;
        gather_w2((const char*)t1, pr, rb0, dg0, rb1, dg1, lane4, g0, g1);
        t2v0 = fmaf(2.f, g0, -t00);
        t2v1 = fmaf(2.f, g1, -t01);
        dense2<CI, CO>(acc0, t2v0, acc1, t2v1, sW, lane);
    }

    if (LAST == 0) {
        accb[node0 * 64 + lane] = acc0;
        accb[node1 * 64 + lane] = acc1;
        t2[node0 * 64 + lane] = t2v0;
        t2[node1 * 64 + lane] = t2v1;
    } else if (LAST == 1) {
        outp[node0 * 64 + lane] = acc0 / (1.f + expf(-acc0));  // silu; lanes>=CO: 0
        outp[node1 * 64 + lane] = acc1 / (1.f + expf(-acc1));
    } else {
        float w4 = (lane < 30) ? W4[lane] : 0.f;
        float h0 = acc0 / (1.f + expf(-acc0));
        float p = h0 * w4;
        p += __shfl_xor(p, 1);
        p += __shfl_xor(p, 2);
        p += __shfl_xor(p, 4);
        p += __shfl_xor(p, 8);
        p += __shfl_xor(p, 16);
        p += __shfl_xor(p, 32);
        if (lane == 0) outp[node0] = 1.f / (1.f + expf(-p));
        float h1 = acc1 / (1.f + expf(-acc1));
        float q = h1 * w4;
        q += __shfl_xor(q, 1);
        q += __shfl_xor(q, 2);
        q += __shfl_xor(q, 4);
        q += __shfl_xor(q, 8);
        q += __shfl_xor(q, 16);
        q += __shfl_xor(q, 32);
        if (lane == 0) outp[node1] = 1.f / (1.f + expf(-q));
    }
}

template <int MODE, int LAST>
__global__ __launch_bounds__(256, 8) void k_narrow(
    const int* __restrict__ rowptr, const int2* __restrict__ pr,
    const float* __restrict__ xin,
    const float* __restrict__ t0, const float* __restrict__ t1,
    float* __restrict__ t2, float* __restrict__ accb,
    const float* __restrict__ Wk, const float* __restrict__ bias,
    float* __restrict__ outp)
{
    __shared__ float sW[(MODE == 1 ? 2 : 1) * 4 * 64];
    int tid = threadIdx.x;
    const int NW = (MODE == 1 ? 2 : 1) * 4 * 64;
    for (int i = tid; i < NW; i += 256) sW[i] = Wk[i];
    __syncthreads();

    int lane = tid & 63;
    int lc = lane & 3, eo = lane >> 2, lc4 = lc * 4;
    int node0 = blockIdx.x * 8 + (tid >> 6) * 2;
    int node1 = node0 + 1;
    int rb0 = rowptr[node0], dg0 = rowptr[node0 + 1] - rb0;
    int rb1 = rowptr[node1], dg1 = rowptr[node1 + 1] - rb1;

    float acc0, acc1, t2v0, t2v1;
    if (MODE == 1) {
        float x0 = xin[node0 * 4 + lc];
        float x1 = xin[node1 * 4 + lc];
        float b = bias[lane];
        acc0 = b; acc1 = b;
        dense2<4, 64>(acc0, x0, acc1, x1, sW, lane);
        t2v0 = gather_n((const char*)xin, pr, rb0, dg0, lc4, eo);
        t2v1 = gather_n((const char*)xin, pr, rb1, dg1, lc4, eo);
        dense2<4, 64>(acc0, t2v0, acc1, t2v1, sW + 4 * 64, lane);
    } else {
        acc0 = accb[node0 * 64 + lane];
        acc1 = accb[node1 * 64 + lane];
        float t00 = t0[node0 * 4 + lc];
        float t01 = t0[node1 * 4 + lc];
        float g0 = gather_n((const char*)t1, pr, rb0, dg0, lc4, eo);
        float g1 = gather_n((const char*)t1, pr, rb1, dg1, lc4, eo);
        t2v0 = fmaf(2.f, g0, -t00);
        t2v1 = fmaf(2.f, g1, -t01);
        dense2<4, 64>(acc0, t2v0, acc1, t2v1, sW, lane);
    }

    if (LAST == 0) {
        accb[node0 * 64 + lane] = acc0;
        accb[node1 * 64 + lane] = acc1;
        if (lane < 4) {
            t2[node0 * 4 + lane] = t2v0;
            t2[node1 * 4 + lane] = t2v1;
        }
    } else {
        outp[node0 * 64 + lane] = acc0 / (1.f + expf(-acc0));
        outp[node1 * 64 + lane] = acc1 / (1.f + expf(-acc1));
    }
}

// ---------------- host ----------------

extern "C" void kernel_launch(void* const* d_in, const int* in_sizes, int n_in,
                              void* d_out, int out_size, void* d_ws, size_t ws_size,
                              hipStream_t stream) {
    const float* x  = (const float*)d_in[0];
    const int*   ei = (const int*)d_in[1];
    const float* ew = (const float*)d_in[2];
    const float* W1 = (const float*)d_in[3];
    const float* b1 = (const float*)d_in[4];
    const float* W2 = (const float*)d_in[5];
    const float* b2 = (const float*)d_in[6];
    const float* W3 = (const float*)d_in[7];
    const float* b3 = (const float*)d_in[8];
    const float* W4 = (const float*)d_in[9];
    float* out = (float*)d_out;

    const int n = N_NODES, E = N_EDGES;

    char* ws = (char*)d_ws;
    size_t off = 0;
    auto alloc = [&](size_t bytes) -> void* {
        void* p = ws + off;
        off += (bytes + 255) & ~(size_t)255;
        return p;
    };
    float* deg    = (float*)alloc(n * 4);     // becomes dis in-place
    int*   cnt    = (int*)alloc(n * 4);
    int*   fill   = (int*)alloc(n * 4);
    int*   rowptr = (int*)alloc((n + 4) * 4);
    float* normw  = (float*)alloc((size_t)E * 4);
    int2*  pr     = (int2*)alloc((size_t)E * 8);
    float* t4a  = (float*)alloc(n * 4 * 4);
    float* t4b  = (float*)alloc(n * 4 * 4);
    float* t4c  = (float*)alloc(n * 4 * 4);
    float* tba  = (float*)alloc(n * 64 * 4);
    float* tbb  = (float*)alloc(n * 64 * 4);
    float* tbc  = (float*)alloc(n * 64 * 4);
    float* accb = (float*)alloc(n * 64 * 4);
    float* h1   = (float*)alloc(n * 64 * 4);
    float* h2   = (float*)alloc(n * 64 * 4);
    (void)ws_size; (void)n_in; (void)in_sizes; (void)out_size;

    // ---- preprocessing: degree, norm, dst-sorted pair-CSR ----
    k_init<<<(n + 255) / 256, 256, 0, stream>>>(deg, cnt, fill, n);
    k_deg <<<(E + 255) / 256, 256, 0, stream>>>(ei, ew, deg, E);
    k_dis <<<(n + 255) / 256, 256, 0, stream>>>(deg, n);
    k_norm<<<(E + 255) / 256, 256, 0, stream>>>(ei, ew, deg, normw, cnt, E);
    k_scan<<<1, 1024, 0, stream>>>(cnt, rowptr, n);
    k_fill<<<(E + 255) / 256, 256, 0, stream>>>(ei, normw, rowptr, fill, pr, E);

    const int G = n / 8;  // 1250 blocks x 256 threads, one wave per TWO nodes

    // ---- Layer 1: K=120, 4 -> 64, silu -> h1 ----
    {
        const int K = 120;
        float* tb[3] = {t4a, t4b, t4c};
        k_narrow<1, 0><<<G, 256, 0, stream>>>(rowptr, pr, x, nullptr, nullptr,
                                              tb[1], accb, W1, b1, nullptr);
        for (int k = 2; k < K; k++) {
            const float* t0p = (k == 2) ? x : tb[(k - 2) % 3];
            const float* t1p = tb[(k - 1) % 3];
            const float* Wk = W1 + (size_t)k * 4 * 64;
            if (k < K - 1)
                k_narrow<2, 0><<<G, 256, 0, stream>>>(rowptr, pr, nullptr, t0p, t1p,
                                                      tb[k % 3], accb, Wk, nullptr, nullptr);
            else
                k_narrow<2, 1><<<G, 256, 0, stream>>>(rowptr, pr, nullptr, t0p, t1p,
                                                      nullptr, accb, Wk, nullptr, h1);
        }
    }

    // ---- Layer 2: K=120, 64 -> 60, silu -> h2 ----
    {
        const int K = 120;
        float* tb[3] = {tba, tbb, tbc};
        k_wide<64, 60, 1, 0><<<G, 256, 0, stream>>>(rowptr, pr, h1, nullptr, nullptr,
                                                    tb[1], accb, W2, b2, nullptr, nullptr);
        for (int k = 2; k < K; k++) {
            const float* t0p = (k == 2) ? h1 : tb[(k - 2) % 3];
            const float* t1p = tb[(k - 1) % 3];
            const float* Wk = W2 + (size_t)k * 64 * 60;
            if (k < K - 1)
                k_wide<64, 60, 2, 0><<<G, 256, 0, stream>>>(rowptr, pr, nullptr, t0p, t1p,
                                                            tb[k % 3], accb, Wk, nullptr,
                                                            nullptr, nullptr);
            else
                k_wide<64, 60, 2, 1><<<G, 256, 0, stream>>>(rowptr, pr, nullptr, t0p, t1p,
                                                            nullptr, accb, Wk, nullptr,
                                                            nullptr, h2);
        }
    }

    // ---- Layer 3 (K=20, 60 -> 30, silu) + fused Layer 4 (30 -> 1, sigmoid) ----
    {
        const int K = 20;
        float* tb[3] = {tba, tbb, tbc};
        k_wide<60, 30, 1, 0><<<G, 256, 0, stream>>>(rowptr, pr, h2, nullptr, nullptr,
                                                    tb[1], accb, W3, b3, nullptr, nullptr);
        for (int k = 2; k < K; k++) {
            const float* t0p = (k == 2) ? h2 : tb[(k - 2) % 3];
            const float* t1p = tb[(k - 1) % 3];
            const float* Wk = W3 + (size_t)k * 60 * 30;
            if (k < K - 1)
                k_wide<60, 30, 2, 0><<<G, 256, 0, stream>>>(rowptr, pr, nullptr, t0p, t1p,
                                                            tb[k % 3], accb, Wk, nullptr,
                                                            nullptr, nullptr);
            else
                k_wide<60, 30, 2, 2><<<G, 256, 0, stream>>>(rowptr, pr, nullptr, t0p, t1p,
                                                            nullptr, accb, Wk, nullptr,
                                                            W4, out);
        }
    }
}